// Round 7
// baseline (108.585 us; speedup 1.0000x reference)
//
#include <hip/hip_runtime.h>
#include <hip/hip_bf16.h>
#include <hip/hip_fp16.h>

typedef _Float16 f16;
typedef __attribute__((ext_vector_type(8))) _Float16 f16x8;
typedef __attribute__((ext_vector_type(4))) float f32x4;

#define DIM     2048
#define BROWS   8192
#define NCOLS   1221      // 111 nodes * 11
#define NPAD    1280      // 10 tiles of 128
#define NNODES  111
#define BM      128
#define BN      128
#define BK      64
#define NKT     (DIM / BK)    // 32 K-steps
#define MT      (BROWS / BM)  // 64
#define NT      (NPAD / BN)   // 10
// B fragment image per (nt, kt): 1024 chunks x 16B = 16 KB.
// chunk c = (kk*8 + g)*64 + l ; lane l (r=l&15,q=l>>4) holds
//   col = g*16 + r , k = kk*32 + q*8 .. +8.
// A tile lives in LDS with the same chunk layout but XOR-swizzled byte
// addresses: swz(a) = a ^ (((a>>8)&3)<<5) ^ (((a>>13)&1)<<4)  (write==read).

// ---------------------------------------------------------------------------
// prep_b: W f32 [111][2048][11] -> Bf f16 fragment-ordered (10 nt x 32 kt)
// ---------------------------------------------------------------------------
__global__ void prep_b(const float* __restrict__ W, f16* __restrict__ Bf) {
    int idx = blockIdx.x * 256 + threadIdx.x;  // 327,680
    int c = idx & 1023, img = idx >> 10;       // img = nt*32 + kt
    int nt = img >> 5, kt = img & 31;
    int kk = c >> 9, g = (c >> 6) & 7, l = c & 63, r = l & 15, q = l >> 4;
    int col = nt * 128 + g * 16 + r;
    int d0  = kt * 64 + kk * 32 + q * 8;
    f16x8 v;
    if (col < NCOLS) {
        int n = col / 11, k = col - n * 11;
        const float* src = W + ((size_t)n * DIM + d0) * 11 + k;
        #pragma unroll
        for (int e = 0; e < 8; ++e) v[e] = (f16)src[(size_t)e * 11];
    } else {
        #pragma unroll
        for (int e = 0; e < 8; ++e) v[e] = (f16)0.f;
    }
    *(f16x8*)(Bf + (size_t)idx * 8) = v;
}

// ---------------------------------------------------------------------------
// GEMM, fused x-conversion (T14 async-split):
//  - A: f32 x -> regs (issued one K-step early) -> cvt f16 -> swizzled ds_write
//  - B: global_load_lds 16B, double-buffered, counted vmcnt(6)
//  - 128x128 tile, BK=64, 8 waves (wave-tile 64x32), MFMA order == r4/r6
// ---------------------------------------------------------------------------
__global__ __launch_bounds__(512) void gemm_f16(const float* __restrict__ X,
                                                const f16* __restrict__ Bf,
                                                f16* __restrict__ Lh) {
    __shared__ __align__(16) f16 As[8192];     // 16 KB, single-buffered, swizzled
    __shared__ __align__(16) f16 Bs[2][8192];  // 2 x 16 KB, fragment-linear

    int bid = blockIdx.x;                      // 640 = 8 XCDs * 80
    int swzb = (bid & 7) * 80 + (bid >> 3);    // same-mt blocks are XCD-local
    int mt = swzb / 10, nt = swzb - mt * 10;

    int t = threadIdx.x, w = t >> 6, l = t & 63, r = l & 15, q = l >> 4;
    int wm = w >> 2, wn = w & 3;               // 2 x 4 wave grid, wave tile 64x32

    // ---- A staging map: arow = t>>2 (0..127), kc = t&3 (16-float k-group) ----
    int arow = t >> 2, kc = t & 3;
    const float* a_src = X + (size_t)(mt * 128 + arow) * DIM + kc * 16;
    int kk_w = kc >> 1, g = arow >> 4, rr = arow & 15;
    int q0 = (kc * 2) & 3, q1 = q0 + 1;
    int wbyte0 = (((kk_w * 8 + g) * 1024) + q0 * 256 + rr * 16) ^ (q0 << 5) ^ (kk_w << 4);
    int wbyte1 = (((kk_w * 8 + g) * 1024) + q1 * 256 + rr * 16) ^ (q1 << 5) ^ (kk_w << 4);
    int ardo = (l * 16) ^ (q << 5);            // per-lane read-offset component

    const f16* bbase = Bf + (size_t)(nt * 32) * 8192 + (size_t)t * 8;

    f32x4 acc[4][2];
    #pragma unroll
    for (int i = 0; i < 4; ++i)
        #pragma unroll
        for (int j = 0; j < 2; ++j) acc[i][j] = (f32x4)0.f;

    f32x4 va0, va1, va2, va3;                  // A f32 staging regs (next tile)

#define LOAD_A(KT)                                                               \
    {                                                                            \
        const float* s_ = a_src + (size_t)(KT) * BK;                             \
        va0 = *(const f32x4*)(s_);      va1 = *(const f32x4*)(s_ + 4);           \
        va2 = *(const f32x4*)(s_ + 8);  va3 = *(const f32x4*)(s_ + 12);          \
    }

#define CVT_WRITE_A()                                                            \
    {                                                                            \
        f16x8 h0, h1;                                                            \
        _Pragma("unroll")                                                        \
        for (int e = 0; e < 4; ++e) {                                            \
            h0[e] = (f16)va0[e]; h0[e + 4] = (f16)va1[e];                        \
            h1[e] = (f16)va2[e]; h1[e + 4] = (f16)va3[e];                        \
        }                                                                        \
        *(f16x8*)((char*)As + wbyte0) = h0;                                      \
        *(f16x8*)((char*)As + wbyte1) = h1;                                      \
    }

#define STAGE_B(KT, CB)                                                          \
    {                                                                            \
        const f16* bsrc = bbase + (size_t)(KT) * 8192;                           \
        _Pragma("unroll")                                                        \
        for (int p = 0; p < 2; ++p) {                                            \
            __builtin_amdgcn_global_load_lds(                                    \
                (const __attribute__((address_space(1))) void*)(bsrc + p * 4096),\
                (__attribute__((address_space(3))) void*)(&Bs[CB][p * 4096 + w * 512]), 16, 0, 0); \
        }                                                                        \
    }

#define COMPUTE(CB)                                                              \
    {                                                                            \
        _Pragma("unroll")                                                        \
        for (int kk = 0; kk < 2; ++kk) {                                         \
            f16x8 af[4], bfr[2];                                                 \
            _Pragma("unroll")                                                    \
            for (int m = 0; m < 4; ++m)                                          \
                af[m] = *(const f16x8*)((char*)As + (kk * 8 + wm * 4 + m) * 1024 \
                                        + (ardo ^ (kk << 4)));                   \
            _Pragma("unroll")                                                    \
            for (int n = 0; n < 2; ++n)                                          \
                bfr[n] = *(const f16x8*)(&Bs[CB][((kk * 8 + wn * 2 + n) * 64 + l) * 8]); \
            _Pragma("unroll")                                                    \
            for (int m = 0; m < 4; ++m)                                          \
                _Pragma("unroll")                                                \
                for (int n = 0; n < 2; ++n)                                      \
                    acc[m][n] = __builtin_amdgcn_mfma_f32_16x16x32_f16(af[m], bfr[n], acc[m][n], 0, 0, 0); \
        }                                                                        \
    }

    // STEP kt: cvt+write A(kt) [regs], prefetch A(kt+1)+B(kt+1), wait B(kt),
    // compute. Issue order keeps cvt's auto-wait counted (A older than B).
#define STEP(KT, CC, CN)                                                         \
    {                                                                            \
        CVT_WRITE_A()                                                            \
        LOAD_A((KT) + 1)                                                         \
        STAGE_B((KT) + 1, CN)                                                    \
        asm volatile("s_waitcnt vmcnt(6) lgkmcnt(0)" ::: "memory");              \
        __builtin_amdgcn_s_barrier();                                            \
        COMPUTE(CC)                                                              \
        asm volatile("s_waitcnt lgkmcnt(0)" ::: "memory");                       \
        __builtin_amdgcn_s_barrier();                                            \
    }

    // prologue: A(0) regs first (older), then B(0) -> buffer 0
    LOAD_A(0)
    STAGE_B(0, 0)

    for (int kt = 0; kt < 30; kt += 2) {
        STEP(kt,     0, 1)
        STEP(kt + 1, 1, 0)
    }
    STEP(30, 0, 1)                             // stages B(31), computes tile 30
    // tail: tile 31 (buffer 1), nothing left to prefetch
    CVT_WRITE_A()
    asm volatile("s_waitcnt vmcnt(0) lgkmcnt(0)" ::: "memory");
    __builtin_amdgcn_s_barrier();
    COMPUTE(1)

#undef LOAD_A
#undef CVT_WRITE_A
#undef STAGE_B
#undef COMPUTE
#undef STEP

    // C write (f16): col = lane&15, row = (lane>>4)*4 + j (verified r1-r6)
    #pragma unroll
    for (int m = 0; m < 4; ++m) {
        int row = mt * 128 + wm * 64 + m * 16 + q * 4;
        #pragma unroll
        for (int n = 0; n < 2; ++n) {
            int col = nt * 128 + wn * 32 + n * 16 + r;
            #pragma unroll
            for (int j = 0; j < 4; ++j)
                Lh[(size_t)(row + j) * NPAD + col] = (f16)acc[m][n][j];
        }
    }
}

// ---------- epilogue: softmax per node (k=11) + 3-level product tree ----------
__global__ void tree_epi(const f16* __restrict__ L, const float* __restrict__ bias,
                         float* __restrict__ out) {
    __shared__ float P[4][NNODES * 11];
    __shared__ f16 R[4][NPAD];
    int w = threadIdx.x >> 6, l = threadIdx.x & 63;
    int row = blockIdx.x * 4 + w;

    const f16x8* src = (const f16x8*)(L + (size_t)row * NPAD);
    f16x8* dst = (f16x8*)R[w];
    dst[l]      = src[l];
    dst[l + 64] = src[l + 64];
    if (l < 32) dst[l + 128] = src[l + 128];

    for (int n = l; n < NNODES; n += 64) {
        float v[11], mx = -1e30f;
        #pragma unroll
        for (int k = 0; k < 11; ++k) { v[k] = (float)R[w][n * 11 + k] + bias[n * 11 + k]; mx = fmaxf(mx, v[k]); }
        float s = 0.f;
        #pragma unroll
        for (int k = 0; k < 11; ++k) { v[k] = __expf(v[k] - mx); s += v[k]; }
        float inv = 1.f / s;
        #pragma unroll
        for (int k = 0; k < 11; ++k) P[w][n * 11 + k] = v[k] * inv;
    }
    __syncthreads();
    const float* Pw = P[w];
    for (int c = l; c < 1000; c += 64) {
        int i  = c / 100;
        int j  = (c % 100) / 10;
        int mm = c % 10;
        float p = Pw[1 + i] * Pw[(1 + i) * 11 + 1 + j] * Pw[(11 + 10 * i + j) * 11 + 1 + mm];
        out[(size_t)row * 1000 + c] = p;
    }
    if (row == 0 && threadIdx.x == 0) out[(size_t)BROWS * 1000] = 0.f;  // penalty
}

extern "C" void kernel_launch(void* const* d_in, const int* in_sizes, int n_in,
                              void* d_out, int out_size, void* d_ws, size_t ws_size,
                              hipStream_t stream) {
    const float* x    = (const float*)d_in[0];
    // d_in[1] = labels (unused)
    const float* W    = (const float*)d_in[2];
    const float* bias = (const float*)d_in[3];
    float* out = (float*)d_out;

    // ws layout:
    //   Bf  f16 fragment-ordered   5,242,880 B
    //   Lh  f16 [8192][1280]      20,971,520 B   (total 26,214,400 B)
    f16* Bf = (f16*)d_ws;
    f16* Lh = (f16*)((char*)d_ws + 5242880);

    prep_b <<<1280, 256, 0, stream>>>(W, Bf);
    gemm_f16<<<MT * NT, 512, 0, stream>>>(x, Bf, Lh);
    tree_epi<<<BROWS / 4, 256, 0, stream>>>(Lh, bias, out);
}

// Round 8
// 104.203 us; speedup vs baseline: 1.0421x; 1.0421x over previous
//
#include <hip/hip_runtime.h>
#include <hip/hip_bf16.h>
#include <hip/hip_fp16.h>

typedef _Float16 f16;
typedef __attribute__((ext_vector_type(8))) _Float16 f16x8;
typedef __attribute__((ext_vector_type(4))) float f32x4;

#define DIM     2048
#define BROWS   8192
#define NCOLS   1221      // 111 nodes * 11
#define NPAD    1280      // 10 panels of 128
#define NNODES  111
#define BK      64
#define NKT     (DIM / BK)    // 32 K-tiles
#define IMG     8192          // f16 per (panel,kt) fragment image (16 KB)
#define PANEL   (32 * IMG)    // f16 per 128-row/col panel (all kt)
// Fragment image per (128-panel, kt): 1024 chunks x 16B.
// chunk c = (kk*8 + g)*64 + l ; lane l (r=l&15,q=l>>4) holds
//   row/col = g*16 + r , k = kk*32 + q*8 .. +8.

// ---------------------------------------------------------------------------
// prep_x: x f32 [8192][2048] -> Xf f16 fragment-ordered (64 panels x 32 kt)
// ---------------------------------------------------------------------------
__global__ __launch_bounds__(256) void prep_x(const float* __restrict__ X,
                                              f16* __restrict__ Xf) {
    __shared__ float T[128 * 68];
    int blk = blockIdx.x;                      // panel*32 + kt
    int mp = blk >> 5, kt = blk & 31;
    int t = threadIdx.x;
    int row = t >> 1, half = t & 1;
    const float* src = X + (size_t)(mp * 128 + row) * DIM + kt * 64 + half * 32;
    float* dst = T + row * 68 + half * 32;
    #pragma unroll
    for (int i = 0; i < 8; ++i) ((f32x4*)dst)[i] = ((const f32x4*)src)[i];
    __syncthreads();
    int w = t >> 6, l = t & 63, r = l & 15, q = l >> 4;
    f16* out = Xf + (size_t)blk * IMG;
    #pragma unroll
    for (int p = 0; p < 4; ++p) {
        int gk = p * 4 + w;                    // = kk*8 + g
        int kk = gk >> 3, g = gk & 7;
        const float* s = T + (g * 16 + r) * 68 + kk * 32 + q * 8;
        f32x4 a = *(const f32x4*)s;
        f32x4 b = *(const f32x4*)(s + 4);
        f16x8 h;
        h[0] = (f16)a[0]; h[1] = (f16)a[1]; h[2] = (f16)a[2]; h[3] = (f16)a[3];
        h[4] = (f16)b[0]; h[5] = (f16)b[1]; h[6] = (f16)b[2]; h[7] = (f16)b[3];
        *(f16x8*)(out + (size_t)(p * 256 + t) * 8) = h;   // coalesced
    }
}

// ---------------------------------------------------------------------------
// prep_b: W f32 [111][2048][11] -> Bf f16 fragment-ordered (10 panels x 32 kt)
// ---------------------------------------------------------------------------
__global__ void prep_b(const float* __restrict__ W, f16* __restrict__ Bf) {
    int idx = blockIdx.x * 256 + threadIdx.x;  // 327,680
    int c = idx & 1023, img = idx >> 10;       // img = panel*32 + kt
    int np = img >> 5, kt = img & 31;
    int kk = c >> 9, g = (c >> 6) & 7, l = c & 63, r = l & 15, q = l >> 4;
    int col = np * 128 + g * 16 + r;
    int d0  = kt * 64 + kk * 32 + q * 8;
    f16x8 v;
    if (col < NCOLS) {
        int n = col / 11, k = col - n * 11;
        const float* src = W + ((size_t)n * DIM + d0) * 11 + k;
        #pragma unroll
        for (int e = 0; e < 8; ++e) v[e] = (f16)src[(size_t)e * 11];
    } else {
        #pragma unroll
        for (int e = 0; e < 8; ++e) v[e] = (f16)0.f;
    }
    *(f16x8*)(Bf + (size_t)idx * 8) = v;
}

// ---------------------------------------------------------------------------
// GEMM: 256x256 tile (2x2 fragment panels), BK=64, 8 waves (wave-tile 128x64),
// double-buffered 128 KB LDS, counted vmcnt(8) depth-1 prefetch (r6 skeleton).
// Thick phase: 64 MFMA/wave per K-tile (~1030 SIMD-cyc) > load latency.
// ---------------------------------------------------------------------------
__global__ __launch_bounds__(512, 2) void gemm_f16(const f16* __restrict__ Xf,
                                                   const f16* __restrict__ Bf,
                                                   f16* __restrict__ Lh) {
    __shared__ __align__(16) f16 As[2][16384];   // 32 KB per buffer (2 panels)
    __shared__ __align__(16) f16 Bs[2][16384];

    int bid = blockIdx.x;                        // 160 = 8 XCDs * 20
    int swz = (bid & 7) * 20 + (bid >> 3);       // per XCD: 4 mt x 5 nt
    int mt = swz / 5, nt = swz - mt * 5;         // mt 0..31, nt 0..4

    int t = threadIdx.x, w = t >> 6, l = t & 63, r = l & 15, q = l >> 4;
    int wm = w >> 2, wn = w & 3;                 // 2 x 4 waves, wave tile 128x64

    const f16* abase = Xf + (size_t)(mt * 2) * PANEL + (size_t)t * 8;
    const f16* bbase = Bf + (size_t)(nt * 2) * PANEL + (size_t)t * 8;

    f32x4 acc[8][4];
    #pragma unroll
    for (int i = 0; i < 8; ++i)
        #pragma unroll
        for (int j = 0; j < 4; ++j) acc[i][j] = (f32x4)0.f;

    // 8 global_load_lds per thread per K-tile: A 32KB (4) + B 32KB (4).
    // load p: panel p>>1, image half p&1.  LDS = chunk-linear concat.
#define STAGE(KT, C)                                                              \
    {                                                                             \
        _Pragma("unroll")                                                         \
        for (int p = 0; p < 4; ++p) {                                             \
            __builtin_amdgcn_global_load_lds(                                     \
                (const __attribute__((address_space(1))) void*)                   \
                    (abase + (size_t)(p >> 1) * PANEL + (size_t)(KT) * IMG + (p & 1) * 4096), \
                (__attribute__((address_space(3))) void*)(&As[C][p * 4096 + w * 512]), 16, 0, 0); \
            __builtin_amdgcn_global_load_lds(                                     \
                (const __attribute__((address_space(1))) void*)                   \
                    (bbase + (size_t)(p >> 1) * PANEL + (size_t)(KT) * IMG + (p & 1) * 4096), \
                (__attribute__((address_space(3))) void*)(&Bs[C][p * 4096 + w * 512]), 16, 0, 0); \
        }                                                                         \
    }

    // per kk: af[8] (panel wm) + bf[4] (panel wn>>1, col-group (wn&1)*4+n)
#define COMPUTE(C)                                                                \
    {                                                                             \
        _Pragma("unroll")                                                         \
        for (int kk = 0; kk < 2; ++kk) {                                          \
            f16x8 af[8], bfr[4];                                                  \
            _Pragma("unroll")                                                     \
            for (int m = 0; m < 8; ++m)                                           \
                af[m] = *(const f16x8*)(&As[C][wm * 8192 + ((kk * 8 + m) * 64 + l) * 8]); \
            _Pragma("unroll")                                                     \
            for (int n = 0; n < 4; ++n)                                           \
                bfr[n] = *(const f16x8*)(&Bs[C][(wn >> 1) * 8192                  \
                            + ((kk * 8 + (wn & 1) * 4 + n) * 64 + l) * 8]);       \
            _Pragma("unroll")                                                     \
            for (int m = 0; m < 8; ++m)                                           \
                _Pragma("unroll")                                                 \
                for (int n = 0; n < 4; ++n)                                       \
                    acc[m][n] = __builtin_amdgcn_mfma_f32_16x16x32_f16(af[m], bfr[n], acc[m][n], 0, 0, 0); \
        }                                                                         \
    }

    // prologue: tile 0 -> buffer 0 (8 loads in flight)
    STAGE(0, 0)

    for (int kt = 0; kt < NKT - 1; ++kt) {
        int cc = kt & 1, cn = cc ^ 1;
        STAGE(kt + 1, cn)                                    // 8 more in flight
        asm volatile("s_waitcnt vmcnt(8)" ::: "memory");     // tile kt landed
        __builtin_amdgcn_s_barrier();
        COMPUTE(cc)
        asm volatile("s_waitcnt lgkmcnt(0)" ::: "memory");   // reads done
        __builtin_amdgcn_s_barrier();                        // buf cn reusable
    }
    // tail: tile 31 (buffer 1)
    asm volatile("s_waitcnt vmcnt(0)" ::: "memory");
    __builtin_amdgcn_s_barrier();
    COMPUTE(1)

#undef STAGE
#undef COMPUTE

    // C write (f16): col = lane&15, row = (lane>>4)*4 + j (verified r1-r6)
    #pragma unroll
    for (int m = 0; m < 8; ++m) {
        int row = mt * 256 + wm * 128 + m * 16 + q * 4;
        #pragma unroll
        for (int n = 0; n < 4; ++n) {
            int col = nt * 256 + wn * 64 + n * 16 + r;
            #pragma unroll
            for (int j = 0; j < 4; ++j)
                Lh[(size_t)(row + j) * NPAD + col] = (f16)acc[m][n][j];
        }
    }
}

// ---------- epilogue: softmax per node (k=11) + 3-level product tree ----------
__global__ void tree_epi(const f16* __restrict__ L, const float* __restrict__ bias,
                         float* __restrict__ out) {
    __shared__ float P[4][NNODES * 11];
    __shared__ f16 R[4][NPAD];
    int w = threadIdx.x >> 6, l = threadIdx.x & 63;
    int row = blockIdx.x * 4 + w;

    const f16x8* src = (const f16x8*)(L + (size_t)row * NPAD);
    f16x8* dst = (f16x8*)R[w];
    dst[l]      = src[l];
    dst[l + 64] = src[l + 64];
    if (l < 32) dst[l + 128] = src[l + 128];

    for (int n = l; n < NNODES; n += 64) {
        float v[11], mx = -1e30f;
        #pragma unroll
        for (int k = 0; k < 11; ++k) { v[k] = (float)R[w][n * 11 + k] + bias[n * 11 + k]; mx = fmaxf(mx, v[k]); }
        float s = 0.f;
        #pragma unroll
        for (int k = 0; k < 11; ++k) { v[k] = __expf(v[k] - mx); s += v[k]; }
        float inv = 1.f / s;
        #pragma unroll
        for (int k = 0; k < 11; ++k) P[w][n * 11 + k] = v[k] * inv;
    }
    __syncthreads();
    const float* Pw = P[w];
    for (int c = l; c < 1000; c += 64) {
        int i  = c / 100;
        int j  = (c % 100) / 10;
        int mm = c % 10;
        float p = Pw[1 + i] * Pw[(1 + i) * 11 + 1 + j] * Pw[(11 + 10 * i + j) * 11 + 1 + mm];
        out[(size_t)row * 1000 + c] = p;
    }
    if (row == 0 && threadIdx.x == 0) out[(size_t)BROWS * 1000] = 0.f;  // penalty
}

extern "C" void kernel_launch(void* const* d_in, const int* in_sizes, int n_in,
                              void* d_out, int out_size, void* d_ws, size_t ws_size,
                              hipStream_t stream) {
    const float* x    = (const float*)d_in[0];
    // d_in[1] = labels (unused)
    const float* W    = (const float*)d_in[2];
    const float* bias = (const float*)d_in[3];
    float* out = (float*)d_out;

    // ws layout:
    //   Xf  f16 fragment-ordered  33,554,432 B
    //   Bf  f16 fragment-ordered   5,242,880 B
    //   Lh  f16 [8192][1280]      20,971,520 B   (total 59,768,832 B)
    f16* Xf = (f16*)d_ws;
    f16* Bf = (f16*)((char*)d_ws + 33554432);
    f16* Lh = (f16*)((char*)d_ws + 38797312);

    prep_x <<<64 * 32, 256, 0, stream>>>(x, Xf);
    prep_b <<<1280, 256, 0, stream>>>(W, Bf);
    gemm_f16<<<160, 512, 0, stream>>>(Xf, Bf, Lh);
    tree_epi<<<BROWS / 4, 256, 0, stream>>>(Lh, bias, out);
}

// Round 10
// 96.046 us; speedup vs baseline: 1.1306x; 1.0849x over previous
//
#include <hip/hip_runtime.h>
#include <hip/hip_bf16.h>
#include <hip/hip_fp16.h>

typedef _Float16 f16;
typedef __attribute__((ext_vector_type(8))) _Float16 f16x8;
typedef __attribute__((ext_vector_type(4))) float f32x4;

#define DIM     2048
#define BROWS   8192
#define NCOLS   1221      // 111 nodes * 11
#define NPAD    1280      // 10 panels of 128
#define NNODES  111
#define BK      64
#define NKT     32
#define IMG     8192          // f16 per (128-panel, kt) fragment image (16 KB)
#define PANEL   (32 * IMG)
// Fragment image per (128-panel, kt): 1024 chunks x 16B.
// chunk c = (kk*8 + g)*64 + l ; lane l (r=l&15,q=l>>4) holds
//   row/col = g*16 + r , k = kk*32 + q*8 .. +8.

// ---------------------------------------------------------------------------
// prep_all: block < 2048 -> prep_x (x f32 -> Xf fragment f16)
//           block >= 2048 -> prep_b (W f32 -> Bf fragment f16)
// ---------------------------------------------------------------------------
__global__ __launch_bounds__(256) void prep_all(const float* __restrict__ X,
                                                const float* __restrict__ W,
                                                f16* __restrict__ Xf,
                                                f16* __restrict__ Bf) {
    __shared__ float T[128 * 68];
    int b = blockIdx.x;
    if (b < 2048) {
        int mp = b >> 5, kt = b & 31;
        int t = threadIdx.x;
        int row = t >> 1, half = t & 1;
        const float* src = X + (size_t)(mp * 128 + row) * DIM + kt * 64 + half * 32;
        float* dst = T + row * 68 + half * 32;
        #pragma unroll
        for (int i = 0; i < 8; ++i) ((f32x4*)dst)[i] = ((const f32x4*)src)[i];
        __syncthreads();
        int w = t >> 6, l = t & 63, r = l & 15, q = l >> 4;
        f16* out = Xf + (size_t)b * IMG;
        #pragma unroll
        for (int p = 0; p < 4; ++p) {
            int gk = p * 4 + w;                // = kk*8 + g
            int kk = gk >> 3, g = gk & 7;
            const float* s = T + (g * 16 + r) * 68 + kk * 32 + q * 8;
            f32x4 a = *(const f32x4*)s;
            f32x4 c = *(const f32x4*)(s + 4);
            f16x8 h;
            h[0] = (f16)a[0]; h[1] = (f16)a[1]; h[2] = (f16)a[2]; h[3] = (f16)a[3];
            h[4] = (f16)c[0]; h[5] = (f16)c[1]; h[6] = (f16)c[2]; h[7] = (f16)c[3];
            *(f16x8*)(out + (size_t)(p * 256 + t) * 8) = h;
        }
    } else {
        int idx = (b - 2048) * 256 + threadIdx.x;   // 0 .. 327679
        int c = idx & 1023, img = idx >> 10;
        int np = img >> 5, kt = img & 31;
        int kk = c >> 9, g = (c >> 6) & 7, l = c & 63, r = l & 15, q = l >> 4;
        int col = np * 128 + g * 16 + r;
        int d0  = kt * 64 + kk * 32 + q * 8;
        f16x8 v;
        if (col < NCOLS) {
            int n = col / 11, k = col - n * 11;
            const float* src = W + ((size_t)n * DIM + d0) * 11 + k;
            #pragma unroll
            for (int e = 0; e < 8; ++e) v[e] = (f16)src[(size_t)e * 11];
        } else {
            #pragma unroll
            for (int e = 0; e < 8; ++e) v[e] = (f16)0.f;
        }
        *(f16x8*)(Bf + (size_t)idx * 8) = v;
    }
}

// ---------------------------------------------------------------------------
// GEMM: 256x256 tile, BK=64, 8 waves (2Mx4N, wave-tile 128x64), dbuf 128KB LDS.
// Phase-split schedule, reads strictly AFTER the availability barrier:
//  Q0: stage A-half0(kt+1) | vmcnt(6) | BAR | read kk0 | lgkm0 | MFMA | BAR
//  Q1: stage B-half0(kt+1) |           read kk0/mh1    | lgkm0 | MFMA | BAR
//  Q2/Q3: same for kk1.  vmcnt never 0 in main loop. MFMA order == r8.
// ---------------------------------------------------------------------------
__global__ __launch_bounds__(512, 2) void gemm_f16(const f16* __restrict__ Xf,
                                                   const f16* __restrict__ Bf,
                                                   f16* __restrict__ Lh) {
    __shared__ __align__(16) f16 As[2][16384];   // 32 KB per buffer
    __shared__ __align__(16) f16 Bs[2][16384];

    int bid = blockIdx.x;                        // 160 = 8 XCDs * 20
    int swz = (bid & 7) * 20 + (bid >> 3);
    int mt = swz / 5, nt = swz - mt * 5;

    int t = threadIdx.x, w = t >> 6, l = t & 63, r = l & 15, q = l >> 4;
    int wm = w >> 2, wn = w & 3;
    int bpan = (wn >> 1) * 8192, bc4 = (wn & 1) * 4;

    const f16* abase = Xf + (size_t)(mt * 2) * PANEL + (size_t)t * 8;
    const f16* bbase = Bf + (size_t)(nt * 2) * PANEL + (size_t)t * 8;

    f32x4 acc[8][4];
    #pragma unroll
    for (int i = 0; i < 8; ++i)
        #pragma unroll
        for (int j = 0; j < 4; ++j) acc[i][j] = (f32x4)0.f;

    f16x8 af[4], bfr[4];

#define GLD(SRC, DST)                                                            \
    __builtin_amdgcn_global_load_lds(                                            \
        (const __attribute__((address_space(1))) void*)(SRC),                    \
        (__attribute__((address_space(3))) void*)(DST), 16, 0, 0)
    // half-tile (operand, KH): 2 loads (panel0 + panel1), KH = kk slice
#define STAGE_A(KT, C, KH)                                                       \
    { GLD(abase + (size_t)(KT) * IMG + (KH) * 4096, &As[C][(KH) * 4096 + w * 512]);            \
      GLD(abase + PANEL + (size_t)(KT) * IMG + (KH) * 4096, &As[C][(2 + (KH)) * 4096 + w * 512]); }
#define STAGE_B(KT, C, KH)                                                       \
    { GLD(bbase + (size_t)(KT) * IMG + (KH) * 4096, &Bs[C][(KH) * 4096 + w * 512]);            \
      GLD(bbase + PANEL + (size_t)(KT) * IMG + (KH) * 4096, &Bs[C][(2 + (KH)) * 4096 + w * 512]); }
#define DS_AF(C, KK, MH)                                                         \
    { _Pragma("unroll")                                                          \
      for (int m_ = 0; m_ < 4; ++m_)                                             \
          af[m_] = *(const f16x8*)(&As[C][wm * 8192 + (((KK) * 8 + (MH) * 4 + m_) * 64 + l) * 8]); }
#define DS_BF(C, KK)                                                             \
    { _Pragma("unroll")                                                          \
      for (int n_ = 0; n_ < 4; ++n_)                                             \
          bfr[n_] = *(const f16x8*)(&Bs[C][bpan + (((KK) * 8 + bc4 + n_) * 64 + l) * 8]); }
#define MFMA16(MH)                                                               \
    { _Pragma("unroll")                                                          \
      for (int m_ = 0; m_ < 4; ++m_)                                             \
          _Pragma("unroll")                                                      \
          for (int n_ = 0; n_ < 4; ++n_)                                         \
              acc[(MH) * 4 + m_][n_] = __builtin_amdgcn_mfma_f32_16x16x32_f16(   \
                  af[m_], bfr[n_], acc[(MH) * 4 + m_][n_], 0, 0, 0); }
#define BAR __builtin_amdgcn_s_barrier()
#define LGKM0 { asm volatile("s_waitcnt lgkmcnt(0)" ::: "memory");               \
                __builtin_amdgcn_sched_barrier(0); }
#define VM(N) asm volatile("s_waitcnt vmcnt(" #N ")" ::: "memory")
#define PRIO1 __builtin_amdgcn_s_setprio(1)
#define PRIO0 __builtin_amdgcn_s_setprio(0)

    // Queue invariant at ITER(kt) entry: outstanding = tile kt's 4 half-tiles
    // (8 loads). VM(6) at Q0 drains A0,B0(kt); at Q2 drains A1,B1(kt).
#define ITER(KT, CC, CN)                                                         \
    { /* Q0 */                                                                   \
      STAGE_A((KT) + 1, CN, 0)                                                   \
      VM(6);                                                                     \
      BAR;                          /* kt kk0 data visible to all waves */       \
      DS_AF(CC, 0, 0) DS_BF(CC, 0)                                               \
      LGKM0 PRIO1; MFMA16(0) PRIO0; BAR;                                         \
      /* Q1 */                                                                   \
      STAGE_B((KT) + 1, CN, 0)                                                   \
      DS_AF(CC, 0, 1)                                                            \
      LGKM0 PRIO1; MFMA16(1) PRIO0; BAR;                                         \
      /* Q2 */                                                                   \
      STAGE_A((KT) + 1, CN, 1)                                                   \
      VM(6);                                                                     \
      BAR;                          /* kt kk1 data visible */                    \
      DS_AF(CC, 1, 0) DS_BF(CC, 1)                                               \
      LGKM0 PRIO1; MFMA16(0) PRIO0; BAR;                                         \
      /* Q3 */                                                                   \
      STAGE_B((KT) + 1, CN, 1)                                                   \
      DS_AF(CC, 1, 1)                                                            \
      LGKM0 PRIO1; MFMA16(1) PRIO0; BAR; }

    // prologue: tile 0 fully staged (8 loads in flight)
    STAGE_A(0, 0, 0) STAGE_B(0, 0, 0) STAGE_A(0, 0, 1) STAGE_B(0, 0, 1)

    for (int kt = 0; kt < 30; kt += 2) {
        ITER(kt,     0, 1)
        ITER(kt + 1, 1, 0)
    }
    ITER(30, 0, 1)                               // stages tile 31 -> buf 1
    // tail: tile 31 (buf 1); entry outstanding = tile 31's 8 loads
    VM(4);                                       // A0,B0(31) landed
    BAR;
    DS_AF(1, 0, 0) DS_BF(1, 0)
    LGKM0 PRIO1; MFMA16(0) PRIO0;
    DS_AF(1, 0, 1)
    LGKM0 PRIO1; MFMA16(1) PRIO0;
    VM(0);                                       // A1,B1(31) landed
    BAR;
    DS_AF(1, 1, 0) DS_BF(1, 1)
    LGKM0 PRIO1; MFMA16(0) PRIO0;
    DS_AF(1, 1, 1)
    LGKM0 PRIO1; MFMA16(1) PRIO0;

#undef GLD
#undef STAGE_A
#undef STAGE_B
#undef DS_AF
#undef DS_BF
#undef MFMA16
#undef BAR
#undef LGKM0
#undef VM
#undef PRIO1
#undef PRIO0
#undef ITER

    // C write (f16): col = lane&15, row = (lane>>4)*4 + j (verified r1-r8)
    #pragma unroll
    for (int m = 0; m < 8; ++m) {
        int row = mt * 256 + wm * 128 + m * 16 + q * 4;
        #pragma unroll
        for (int n = 0; n < 4; ++n) {
            int col = nt * 256 + wn * 64 + n * 16 + r;
            #pragma unroll
            for (int j = 0; j < 4; ++j)
                Lh[(size_t)(row + j) * NPAD + col] = (f16)acc[m][n][j];
        }
    }
}

// ---------- epilogue: softmax per node (k=11) + 3-level product tree ----------
__global__ void tree_epi(const f16* __restrict__ L, const float* __restrict__ bias,
                         float* __restrict__ out) {
    __shared__ float P[4][NNODES * 11];
    __shared__ f16 R[4][NPAD];
    int w = threadIdx.x >> 6, l = threadIdx.x & 63;
    int row = blockIdx.x * 4 + w;

    const f16x8* src = (const f16x8*)(L + (size_t)row * NPAD);
    f16x8* dst = (f16x8*)R[w];
    dst[l]      = src[l];
    dst[l + 64] = src[l + 64];
    if (l < 32) dst[l + 128] = src[l + 128];

    for (int n = l; n < NNODES; n += 64) {
        float v[11], mx = -1e30f;
        #pragma unroll
        for (int k = 0; k < 11; ++k) { v[k] = (float)R[w][n * 11 + k] + bias[n * 11 + k]; mx = fmaxf(mx, v[k]); }
        float s = 0.f;
        #pragma unroll
        for (int k = 0; k < 11; ++k) { v[k] = __expf(v[k] - mx); s += v[k]; }
        float inv = 1.f / s;
        #pragma unroll
        for (int k = 0; k < 11; ++k) P[w][n * 11 + k] = v[k] * inv;
    }
    __syncthreads();
    const float* Pw = P[w];
    for (int c = l; c < 1000; c += 64) {
        int i  = c / 100;
        int j  = (c % 100) / 10;
        int mm = c % 10;
        float p = Pw[1 + i] * Pw[(1 + i) * 11 + 1 + j] * Pw[(11 + 10 * i + j) * 11 + 1 + mm];
        out[(size_t)row * 1000 + c] = p;
    }
    if (row == 0 && threadIdx.x == 0) out[(size_t)BROWS * 1000] = 0.f;  // penalty
}

extern "C" void kernel_launch(void* const* d_in, const int* in_sizes, int n_in,
                              void* d_out, int out_size, void* d_ws, size_t ws_size,
                              hipStream_t stream) {
    const float* x    = (const float*)d_in[0];
    // d_in[1] = labels (unused)
    const float* W    = (const float*)d_in[2];
    const float* bias = (const float*)d_in[3];
    float* out = (float*)d_out;

    // ws layout:
    //   Xf  f16 fragment-ordered  33,554,432 B
    //   Bf  f16 fragment-ordered   5,242,880 B
    //   Lh  f16 [8192][1280]      20,971,520 B   (total 59,768,832 B)
    f16* Xf = (f16*)d_ws;
    f16* Bf = (f16*)((char*)d_ws + 33554432);
    f16* Lh = (f16*)((char*)d_ws + 38797312);

    prep_all<<<2048 + 1280, 256, 0, stream>>>(x, W, Xf, Bf);
    gemm_f16<<<160, 512, 0, stream>>>(Xf, Bf, Lh);
    tree_epi<<<BROWS / 4, 256, 0, stream>>>(Lh, bias, out);
}